// Round 5
// baseline (256.970 us; speedup 1.0000x reference)
//
#include <hip/hip_runtime.h>
#include <cstdint>
#include <cstddef>

#define NF 256   // features
#define NG 512   // hidden (2F)
#define NC 64    // classes
#define NB 8192  // batch
#define NK 16    // active rules
#define BT 64    // fs batch tile

typedef __attribute__((ext_vector_type(8))) short short8;
typedef __attribute__((ext_vector_type(4))) float floatx4;

__device__ __forceinline__ unsigned short f2bf(float f) {
    union { float f; unsigned int u; } a; a.f = f;
    unsigned int u = a.u;
    u += 0x7fffu + ((u >> 16) & 1u);   // RNE
    return (unsigned short)(u >> 16);
}
__device__ __forceinline__ float elu1(float z) {
    return z > 0.0f ? z : (__expf(z) - 1.0f);
}

// ---------------- kernel 0: weights fp32 -> bf16 in workspace ----------------
// layout (ushort elements): [0,131072) W1b | [131072,262144) W2b | [262144,786432) Wcb
__global__ __launch_bounds__(256) void conv_kernel(
    const float* __restrict__ W1, const float* __restrict__ W2,
    const float* __restrict__ Wc, unsigned short* __restrict__ wb)
{
    int i = blockIdx.x * 256 + threadIdx.x;
    if (i < 131072)       wb[i] = f2bf(W1[i]);
    else if (i < 262144)  wb[i] = f2bf(W2[i - 131072]);
    else if (i < 786432)  wb[i] = f2bf(Wc[i - 262144]);
}

// ---------------- kernel 1: fused membership -> MLP -> fsi ----------------
// grid: 2048 blocks = 16 rules x 128 batch tiles; 256 threads (4 waves).
// LDS 48 KB: mv [64][256] bf16 (32 KB, whole) + cbuf [64][128] (16 KB,
// sub-chunk inter-layer buffer) -> 3 blocks/CU, 12 waves/CU, THREE independent
// barrier rhythms per CU (R0-R4 all had <=2). Reg target 170 via
// __launch_bounds__(256,3); no hand prefetch (R3/R4 proved it neutral; the
// freed regs let the compiler pipeline the unrolled loops itself).
// h1 computed in 4 sub-chunks of 128 cols; P2 accumulates k = s*128..s*128+128
// per sub-chunk (same overall k-order as R4 -> identical FP results).
// s_setprio(1) wraps each MFMA cluster (T5: pays when co-resident blocks are
// at different phases, which 3 blocks/CU provides).
__global__ __launch_bounds__(256, 3) void fs_kernel(
    const float* __restrict__ x, const float* __restrict__ proto,
    const float* __restrict__ var, const unsigned short* __restrict__ W1b,
    const float* __restrict__ b1, const unsigned short* __restrict__ W2b,
    const float* __restrict__ b2, const float* __restrict__ W3,
    const float* __restrict__ b3, const int* __restrict__ ridx,
    float* __restrict__ fsi)
{
    extern __shared__ unsigned short smem[];
    unsigned short* mv   = smem;              // [64][256] swizzled (512 B rows)
    unsigned short* cbuf = smem + 64 * 256;   // [64][128] swizzled (256 B rows); part[] in P3

    const int t    = threadIdx.x;
    const int kidx = blockIdx.x & 15;
    const int tile = blockIdx.x >> 4;
    const int r    = ridx[kidx];
    const int b0   = tile * BT;

    const int wave = t >> 6, lane = t & 63;
    const int ln = lane & 15, lq = lane >> 4;
    const int sxr = (ln & 7) << 4;            // swizzle term (row&7 == ln&7)

    // ---- phase 0: membership mv = exp(-(x-p)^2 / (2 v^2)), v=clip(var,1e-4,0.1) ----
    {
        const int col   = (t & 63) * 4;
        const int colb  = (t & 63) * 8;     // byte offset in row
        const int rbase = t >> 6;           // 0..3
        const float4 p4 = *(const float4*)(proto + (size_t)r * NF + col);
        float4 v4 = *(const float4*)(var + (size_t)r * NF + col);
        float cx = fminf(fmaxf(v4.x, 1e-4f), 0.1f);
        float cy = fminf(fmaxf(v4.y, 1e-4f), 0.1f);
        float cz = fminf(fmaxf(v4.z, 1e-4f), 0.1f);
        float cw = fminf(fmaxf(v4.w, 1e-4f), 0.1f);
        float ix = 0.5f / (cx * cx), iy = 0.5f / (cy * cy);
        float iz = 0.5f / (cz * cz), iw = 0.5f / (cw * cw);
#pragma unroll
        for (int i = 0; i < 16; ++i) {
            int row = i * 4 + rbase;
            const float4 xv = *(const float4*)(x + (size_t)(b0 + row) * NF + col);
            float dx = xv.x - p4.x, dy = xv.y - p4.y, dz = xv.z - p4.z, dw = xv.w - p4.w;
            union { unsigned short s[4]; uint2 v; } pk;
            pk.s[0] = f2bf(__expf(-dx * dx * ix));
            pk.s[1] = f2bf(__expf(-dy * dy * iy));
            pk.s[2] = f2bf(__expf(-dz * dz * iz));
            pk.s[3] = f2bf(__expf(-dw * dw * iw));
            *(uint2*)((char*)mv + row * 512 + (colb ^ ((row & 7) << 4))) = pk.v;
        }
    }
    __syncthreads();

    // persistent h2 accumulator: wave owns n' in [wave*64, wave*64+64), all 64 b.
    // lane: n' = wave*64 + mi*16 + lq*4 + rg ; b = ni*16 + ln
    floatx4 acc2[4][4];
#pragma unroll
    for (int mi = 0; mi < 4; ++mi)
#pragma unroll
        for (int ni = 0; ni < 4; ++ni) {
            floatx4 z = {0.0f, 0.0f, 0.0f, 0.0f};
            acc2[mi][ni] = z;
        }

#pragma unroll
    for (int s = 0; s < 4; ++s) {
        // ---- GEMM1 sub-chunk s: h1 cols [s*128, s*128+128) ----
        // A = W1 rows (global L2), B = mv (LDS). Wave n-slice = 32 (2 mi).
        floatx4 acc1[2][4];
#pragma unroll
        for (int mi = 0; mi < 2; ++mi)
#pragma unroll
            for (int ni = 0; ni < 4; ++ni) {
                floatx4 z = {0.0f, 0.0f, 0.0f, 0.0f};
                acc1[mi][ni] = z;
            }
#pragma unroll
        for (int k0i = 0; k0i < 8; ++k0i) {
            short8 a[2];
#pragma unroll
            for (int mi = 0; mi < 2; ++mi)
                a[mi] = *(const short8*)(W1b + (size_t)(s * 128 + wave * 32 + mi * 16 + ln) * NF
                                         + k0i * 32 + lq * 8);
            short8 b[4];
#pragma unroll
            for (int ni = 0; ni < 4; ++ni)
                b[ni] = *(const short8*)((const char*)mv + (ni * 16 + ln) * 512
                                         + ((k0i * 64 + lq * 16) ^ sxr));
            __builtin_amdgcn_s_setprio(1);
#pragma unroll
            for (int ni = 0; ni < 4; ++ni)
#pragma unroll
                for (int mi = 0; mi < 2; ++mi)
                    acc1[mi][ni] = __builtin_amdgcn_mfma_f32_16x16x32_bf16(
                        a[mi], b[ni], acc1[mi][ni], 0, 0, 0);
            __builtin_amdgcn_s_setprio(0);
        }
        __syncthreads();   // prior sub-chunk's P2 reads of cbuf are done
        // ---- ELU + bias -> cbuf (swizzled, 256 B rows) ----
#pragma unroll
        for (int mi = 0; mi < 2; ++mi) {
            const int nl = wave * 32 + mi * 16 + lq * 4;      // sub-chunk-local n
            const float4 b4 = *(const float4*)(b1 + s * 128 + nl);
#pragma unroll
            for (int ni = 0; ni < 4; ++ni) {
                union { unsigned short us[4]; uint2 v; } pk;
                pk.us[0] = f2bf(elu1(acc1[mi][ni][0] + b4.x));
                pk.us[1] = f2bf(elu1(acc1[mi][ni][1] + b4.y));
                pk.us[2] = f2bf(elu1(acc1[mi][ni][2] + b4.z));
                pk.us[3] = f2bf(elu1(acc1[mi][ni][3] + b4.w));
                *(uint2*)((char*)cbuf + (ni * 16 + ln) * 256 + ((nl * 2) ^ sxr)) = pk.v;
            }
        }
        __syncthreads();
        // ---- P2 sub-chunk s: acc2 += W2[:, s*128:+128] @ h1_s^T ----
        // A = W2 rows (global L2), B = cbuf (LDS). 16 MFMA per k0-step.
#pragma unroll
        for (int k0i = 0; k0i < 4; ++k0i) {
            short8 a[4];
#pragma unroll
            for (int mi = 0; mi < 4; ++mi)
                a[mi] = *(const short8*)(W2b + (size_t)(wave * 64 + mi * 16 + ln) * NG
                                         + s * 128 + k0i * 32 + lq * 8);
            short8 b[4];
#pragma unroll
            for (int ni = 0; ni < 4; ++ni)
                b[ni] = *(const short8*)((const char*)cbuf + (ni * 16 + ln) * 256
                                         + ((k0i * 64 + lq * 16) ^ sxr));
            __builtin_amdgcn_s_setprio(1);
#pragma unroll
            for (int ni = 0; ni < 4; ++ni)
#pragma unroll
                for (int mi = 0; mi < 4; ++mi)
                    acc2[mi][ni] = __builtin_amdgcn_mfma_f32_16x16x32_bf16(
                        a[mi], b[ni], acc2[mi][ni], 0, 0, 0);
            __builtin_amdgcn_s_setprio(0);
        }
    }

    // ---- phase 3: fsi[b] = b3 + sum_n' ELU(h2[b][n'] + b2) * W3[n'] ----
    __syncthreads();                 // last P2's cbuf reads done; reuse cbuf as part[4][64]
    float* part = (float*)cbuf;
    float w3v[4][4], b2v[4][4];
#pragma unroll
    for (int mi = 0; mi < 4; ++mi) {
        const int np = wave * 64 + mi * 16 + lq * 4;
        const float4 wv = *(const float4*)(W3 + np);
        const float4 bv = *(const float4*)(b2 + np);
        w3v[mi][0] = wv.x; w3v[mi][1] = wv.y; w3v[mi][2] = wv.z; w3v[mi][3] = wv.w;
        b2v[mi][0] = bv.x; b2v[mi][1] = bv.y; b2v[mi][2] = bv.z; b2v[mi][3] = bv.w;
    }
#pragma unroll
    for (int ni = 0; ni < 4; ++ni) {
        float s = 0.0f;
#pragma unroll
        for (int mi = 0; mi < 4; ++mi)
#pragma unroll
            for (int rg = 0; rg < 4; ++rg)
                s += elu1(acc2[mi][ni][rg] + b2v[mi][rg]) * w3v[mi][rg];
        s += __shfl_xor(s, 16);
        s += __shfl_xor(s, 32);
        if (lq == 0) part[wave * 64 + ni * 16 + ln] = s;
    }
    __syncthreads();
    if (t < 64) {
        float s = b3[0];
#pragma unroll
        for (int w = 0; w < 4; ++w) s += part[w * 64 + t];
        fsi[(size_t)kidx * NB + b0 + t] = s;
    }
}

// ---------------- kernel 2: softmax over rules + consequent + weighted sum ----------------
// grid: 512 blocks x 512 threads; block = 16 batch rows, 64 classes.
// Waves 0-3 handle rules 0-7, waves 4-7 handle rules 8-15 (2x wave parallelism,
// 16 waves/CU); dual-rule unroll gives 2 independent MFMA chains per wave.
__global__ __launch_bounds__(512, 4) void cons_kernel(
    const float* __restrict__ x, const unsigned short* __restrict__ Wcb,
    const float* __restrict__ bc, const float* __restrict__ fsi,
    const int* __restrict__ ridx, float* __restrict__ outp,
    float* __restrict__ fire_out)
{
    __shared__ unsigned short xl[16 * 264];
    __shared__ float fire[16][NK];
    __shared__ float pred[4][16][16];   // half-1 partials: [class-grp][row][class]

    const int t  = threadIdx.x;
    const int b0 = blockIdx.x * 16;

    int rr[NK];
#pragma unroll
    for (int k = 0; k < NK; ++k) rr[k] = ridx[k];

    // x -> bf16 LDS (16 rows x 256 cols, 512 threads x 2 float4)
    {
        int idx = t;
#pragma unroll
        for (int i = 0; i < 2; ++i, idx += 512) {
            int row = idx >> 6, col = (idx & 63) * 4;
            const float4 xv = *(const float4*)(x + (size_t)(b0 + row) * NF + col);
            union { unsigned short s[4]; uint2 v; } pk;
            pk.s[0] = f2bf(xv.x); pk.s[1] = f2bf(xv.y);
            pk.s[2] = f2bf(xv.z); pk.s[3] = f2bf(xv.w);
            *(uint2*)(xl + row * 264 + col) = pk.v;
        }
    }
    // softmax over 16 rules, fully parallel: thread = (row = t>>4, k = t&15)
    if (t < 256) {
        const int row = t >> 4, k = t & 15;
        float v = fsi[(size_t)k * NB + b0 + row];
        float mx = v;
        mx = fmaxf(mx, __shfl_xor(mx, 1));
        mx = fmaxf(mx, __shfl_xor(mx, 2));
        mx = fmaxf(mx, __shfl_xor(mx, 4));
        mx = fmaxf(mx, __shfl_xor(mx, 8));
        float e = __expf(v - mx);
        float sum = e;
        sum += __shfl_xor(sum, 1);
        sum += __shfl_xor(sum, 2);
        sum += __shfl_xor(sum, 4);
        sum += __shfl_xor(sum, 8);
        float fv = e / sum;
        fire[row][k] = fv;
        fire_out[(size_t)b0 * NK + t] = fv;   // (b0+row)*16 + k == b0*16 + t
    }
    __syncthreads();

    const int wave = t >> 6, lane = t & 63;
    const int ln = lane & 15, lq = lane >> 4;
    const int cg = wave & 3, half = wave >> 2;
    const int nb = cg * 16;

    // A-fragments (x tile) cached in registers, reused across this half's 8 rules
    short8 afr[8];
#pragma unroll
    for (int k0i = 0; k0i < 8; ++k0i)
        afr[k0i] = *(const short8*)(xl + ln * 264 + k0i * 32 + lq * 8);

    floatx4 oacc = {0.0f, 0.0f, 0.0f, 0.0f};
#pragma unroll
    for (int kp = 0; kp < 4; ++kp) {
        const int k0r = half * 8 + kp * 2;
        const int r0 = rr[k0r], r1 = rr[k0r + 1];
        const unsigned short* Wr0 = Wcb + ((size_t)r0 * NC + nb + ln) * NF;
        const unsigned short* Wr1 = Wcb + ((size_t)r1 * NC + nb + ln) * NF;
        floatx4 a0 = {0.0f, 0.0f, 0.0f, 0.0f};
        floatx4 a1 = {0.0f, 0.0f, 0.0f, 0.0f};
#pragma unroll
        for (int k0i = 0; k0i < 8; ++k0i) {
            short8 bb0 = *(const short8*)(Wr0 + k0i * 32 + lq * 8);
            short8 bb1 = *(const short8*)(Wr1 + k0i * 32 + lq * 8);
            a0 = __builtin_amdgcn_mfma_f32_16x16x32_bf16(afr[k0i], bb0, a0, 0, 0, 0);
            a1 = __builtin_amdgcn_mfma_f32_16x16x32_bf16(afr[k0i], bb1, a1, 0, 0, 0);
        }
        const float bias0 = bc[(size_t)r0 * NC + nb + ln];
        const float bias1 = bc[(size_t)r1 * NC + nb + ln];
#pragma unroll
        for (int rg = 0; rg < 4; ++rg) {
            const int row = lq * 4 + rg;
            oacc[rg] += fmaxf(a0[rg] + bias0, 0.0f) * fire[row][k0r]
                      + fmaxf(a1[rg] + bias1, 0.0f) * fire[row][k0r + 1];
        }
    }
    if (half == 1) {
#pragma unroll
        for (int rg = 0; rg < 4; ++rg)
            pred[cg][lq * 4 + rg][ln] = oacc[rg];
    }
    __syncthreads();
    if (half == 0) {
#pragma unroll
        for (int rg = 0; rg < 4; ++rg)
            outp[(size_t)(b0 + lq * 4 + rg) * NC + nb + ln] =
                oacc[rg] + pred[cg][lq * 4 + rg][ln];
    }
}

extern "C" void kernel_launch(void* const* d_in, const int* in_sizes, int n_in,
                              void* d_out, int out_size, void* d_ws, size_t ws_size,
                              hipStream_t stream)
{
    (void)in_sizes; (void)n_in; (void)out_size;
    if (ws_size < 2097152) return;  // 1.5MB bf16 weights + 0.5MB fsi

    const float* x     = (const float*)d_in[0];
    const float* proto = (const float*)d_in[1];
    const float* var   = (const float*)d_in[2];
    const float* W1    = (const float*)d_in[3];
    const float* b1    = (const float*)d_in[4];
    const float* W2    = (const float*)d_in[5];
    const float* b2    = (const float*)d_in[6];
    const float* W3    = (const float*)d_in[7];
    const float* b3    = (const float*)d_in[8];
    const float* Wc    = (const float*)d_in[9];
    const float* bc    = (const float*)d_in[10];
    const int*   ridx  = (const int*)d_in[11];

    unsigned short* wb  = (unsigned short*)d_ws;
    unsigned short* W1b = wb;                 // 131072
    unsigned short* W2b = wb + 131072;        // 131072
    unsigned short* Wcb = wb + 262144;        // 524288
    float* fsi = (float*)((char*)d_ws + (size_t)786432 * 2);  // 16*8192 floats

    float* outp     = (float*)d_out;
    float* fire_out = outp + (size_t)NB * NC;

    conv_kernel<<<3072, 256, 0, stream>>>(W1, W2, Wc, wb);

    const int fs_lds = (64 * 256 + 64 * 128) * 2;  // 49152 B
    hipFuncSetAttribute((const void*)fs_kernel,
                        hipFuncAttributeMaxDynamicSharedMemorySize, fs_lds);
    fs_kernel<<<2048, 256, fs_lds, stream>>>(x, proto, var, W1b, b1, W2b, b2,
                                             W3, b3, ridx, fsi);
    cons_kernel<<<512, 512, 0, stream>>>(x, Wcb, bc, fsi, ridx, outp, fire_out);
}

// Round 6
// 245.724 us; speedup vs baseline: 1.0458x; 1.0458x over previous
//
#include <hip/hip_runtime.h>
#include <cstdint>
#include <cstddef>

#define NF 256   // features
#define NG 512   // hidden (2F)
#define NC 64    // classes
#define NB 8192  // batch
#define NK 16    // active rules
#define BT 64    // fs batch tile

typedef __attribute__((ext_vector_type(8))) short short8;
typedef __attribute__((ext_vector_type(4))) float floatx4;

__device__ __forceinline__ unsigned short f2bf(float f) {
    union { float f; unsigned int u; } a; a.f = f;
    unsigned int u = a.u;
    u += 0x7fffu + ((u >> 16) & 1u);   // RNE
    return (unsigned short)(u >> 16);
}
__device__ __forceinline__ float elu1(float z) {
    return z > 0.0f ? z : (__expf(z) - 1.0f);
}

// LDS-only barrier: orders ds ops across the workgroup WITHOUT draining vmcnt.
// Register-destined global loads (weight operands) stay in flight across it
// (T4 adapted; __syncthreads would emit s_waitcnt vmcnt(0) and kill the
// cross-barrier prefetch). sched_barrier(0) fences pin memory-op ordering
// around the inline-asm waitcnt (rule #18).
__device__ __forceinline__ void bar_lds() {
    __builtin_amdgcn_sched_barrier(0);
    asm volatile("s_waitcnt lgkmcnt(0)" ::: "memory");
    __builtin_amdgcn_s_barrier();
    __builtin_amdgcn_sched_barrier(0);
}

// ELU + bias + bf16-pack + swizzled LDS store for one mi-row of an acc tile.
// acc[ni][rg]: n' = nl + rg (4 consecutive), b = ni*16 + ln.
__device__ __forceinline__ void elu_write_row(
    unsigned short* dst, const floatx4* acc, float4 b4, int nl, int ln, int sxr)
{
#pragma unroll
    for (int ni = 0; ni < 4; ++ni) {
        union { unsigned short s[4]; uint2 v; } pk;
        pk.s[0] = f2bf(elu1(acc[ni][0] + b4.x));
        pk.s[1] = f2bf(elu1(acc[ni][1] + b4.y));
        pk.s[2] = f2bf(elu1(acc[ni][2] + b4.z));
        pk.s[3] = f2bf(elu1(acc[ni][3] + b4.w));
        *(uint2*)((char*)dst + (ni * 16 + ln) * 512 + ((nl * 2) ^ sxr)) = pk.v;
    }
}

// ---------------- kernel 0: weights fp32 -> bf16 in workspace ----------------
// layout (ushort elements): [0,131072) W1b | [131072,262144) W2b | [262144,786432) Wcb
__global__ __launch_bounds__(256) void conv_kernel(
    const float* __restrict__ W1, const float* __restrict__ W2,
    const float* __restrict__ Wc, unsigned short* __restrict__ wb)
{
    int i = blockIdx.x * 256 + threadIdx.x;
    if (i < 131072)       wb[i] = f2bf(W1[i]);
    else if (i < 262144)  wb[i] = f2bf(W2[i - 131072]);
    else if (i < 786432)  wb[i] = f2bf(Wc[i - 262144]);
}

// ---------------- kernel 1: fused membership -> MLP -> fsi ----------------
// grid: 2048 blocks = 16 rules x 128 batch tiles; 256 threads (4 waves).
// R4 structure (best base, 150us) + two changes:
//  (a) bar_lds() barriers: lgkmcnt-only, so the cross-seam weight prefetches
//      survive the barrier (R4 drained them -> prefetch was dead).
//  (b) XCD-chunked block swizzle (bijective, 2048%8==0): XCD k gets 16
//      consecutive tiles x all 16 rules -> per-XCD x-slice = 1 MB, fetched
//      once into L2 instead of every tile in all 8 XCDs.
__global__ __launch_bounds__(256, 2) void fs_kernel(
    const float* __restrict__ x, const float* __restrict__ proto,
    const float* __restrict__ var, const unsigned short* __restrict__ W1b,
    const float* __restrict__ b1, const unsigned short* __restrict__ W2b,
    const float* __restrict__ b2, const float* __restrict__ W3,
    const float* __restrict__ b3, const int* __restrict__ ridx,
    float* __restrict__ fsi)
{
    extern __shared__ unsigned short smem[];
    unsigned short* mv   = smem;              // [64][256] swizzled; cbuf1 after P1
    unsigned short* cbuf = smem + 64 * 256;   // [64][256] swizzled; part[] in P3

    const int t   = threadIdx.x;
    // XCD-chunked swizzle: physical pid -> logical wg (default XCD = pid%8)
    const int pid = blockIdx.x;
    const int lg  = (pid & 7) * 256 + (pid >> 3);
    const int kidx = lg & 15;
    const int tile = lg >> 4;
    const int r    = ridx[kidx];
    const int b0   = tile * BT;

    const int wave = t >> 6, lane = t & 63;
    const int ln = lane & 15, lq = lane >> 4;
    const int sxr = (ln & 7) << 4;            // swizzle term (row&7 == ln&7)

    // row bases for A-operand (weights) fetches
    const unsigned short* W1base = W1b + (size_t)(wave * 64 + ln) * NF + lq * 8;
    const unsigned short* W2base = W2b + (size_t)(wave * 64 + ln) * NG + lq * 8;

    // ---- issue W1 chunk0/k0=0 fragments now; they land during P0's exp work ----
    short8 a_cur[4], a_nxt[4];
#pragma unroll
    for (int mi = 0; mi < 4; ++mi)
        a_cur[mi] = *(const short8*)(W1base + mi * 16 * NF);

    // ---- phase 0: membership mv = exp(-(x-p)^2 / (2 v^2)), v=clip(var,1e-4,0.1) ----
    {
        const int col   = (t & 63) * 4;
        const int colb  = (t & 63) * 8;     // byte offset in row
        const int rbase = t >> 6;           // 0..3
        const float4 p4 = *(const float4*)(proto + (size_t)r * NF + col);
        float4 v4 = *(const float4*)(var + (size_t)r * NF + col);
        float cx = fminf(fmaxf(v4.x, 1e-4f), 0.1f);
        float cy = fminf(fmaxf(v4.y, 1e-4f), 0.1f);
        float cz = fminf(fmaxf(v4.z, 1e-4f), 0.1f);
        float cw = fminf(fmaxf(v4.w, 1e-4f), 0.1f);
        float ix = 0.5f / (cx * cx), iy = 0.5f / (cy * cy);
        float iz = 0.5f / (cz * cz), iw = 0.5f / (cw * cw);
#pragma unroll
        for (int i = 0; i < 16; ++i) {
            int row = i * 4 + rbase;
            const float4 xv = *(const float4*)(x + (size_t)(b0 + row) * NF + col);
            float dx = xv.x - p4.x, dy = xv.y - p4.y, dz = xv.z - p4.z, dw = xv.w - p4.w;
            union { unsigned short s[4]; uint2 v; } pk;
            pk.s[0] = f2bf(__expf(-dx * dx * ix));
            pk.s[1] = f2bf(__expf(-dy * dy * iy));
            pk.s[2] = f2bf(__expf(-dz * dz * iz));
            pk.s[3] = f2bf(__expf(-dw * dw * iw));
            *(uint2*)((char*)mv + row * 512 + (colb ^ ((row & 7) << 4))) = pk.v;
        }
    }
    bar_lds();

    // chunk-0 biases for the interleaved ELU in P1-chunk1
    float4 bi0[4];
#pragma unroll
    for (int mi = 0; mi < 4; ++mi)
        bi0[mi] = *(const float4*)(b1 + wave * 64 + mi * 16 + lq * 4);

    short8 b_cur[4];
    floatx4 acc1a[4][4], acc1b[4][4];
#pragma unroll
    for (int mi = 0; mi < 4; ++mi)
#pragma unroll
        for (int ni = 0; ni < 4; ++ni) {
            floatx4 z = {0.0f, 0.0f, 0.0f, 0.0f};
            acc1a[mi][ni] = z; acc1b[mi][ni] = z;
        }

    // ================= P1 super-region: 16 steps, no internal barrier =========
    // ---- chunk 0 (W1 rows [0,256)) ----
#pragma unroll
    for (int k0i = 0; k0i < 8; ++k0i) {
#pragma unroll
        for (int ni = 0; ni < 4; ++ni)
            b_cur[ni] = *(const short8*)((const char*)mv + (ni * 16 + ln) * 512
                                         + ((k0i * 64 + lq * 16) ^ sxr));
        const unsigned short* an = (k0i < 7) ? W1base + (k0i + 1) * 32
                                             : W1base + 256 * NF;   // chunk1 k0=0
#pragma unroll
        for (int mi = 0; mi < 4; ++mi)
            a_nxt[mi] = *(const short8*)(an + mi * 16 * NF);
#pragma unroll
        for (int ni = 0; ni < 4; ++ni)
#pragma unroll
            for (int mi = 0; mi < 4; ++mi)
                acc1a[mi][ni] = __builtin_amdgcn_mfma_f32_16x16x32_bf16(
                    a_cur[mi], b_cur[ni], acc1a[mi][ni], 0, 0, 0);
#pragma unroll
        for (int mi = 0; mi < 4; ++mi) a_cur[mi] = a_nxt[mi];
    }
    // ---- chunk 1 (W1 rows [256,512)) + interleaved ELU(chunk0) -> cbuf ----
#pragma unroll
    for (int k0i = 0; k0i < 8; ++k0i) {
#pragma unroll
        for (int ni = 0; ni < 4; ++ni)
            b_cur[ni] = *(const short8*)((const char*)mv + (ni * 16 + ln) * 512
                                         + ((k0i * 64 + lq * 16) ^ sxr));
        const unsigned short* an = (k0i < 7) ? W1base + 256 * NF + (k0i + 1) * 32
                                             : W2base;              // P2 chunk0 k0=0
#pragma unroll
        for (int mi = 0; mi < 4; ++mi)
            a_nxt[mi] = *(const short8*)(an + mi * ((k0i < 7) ? 16 * NF : 16 * NG));
#pragma unroll
        for (int ni = 0; ni < 4; ++ni)
#pragma unroll
            for (int mi = 0; mi < 4; ++mi)
                acc1b[mi][ni] = __builtin_amdgcn_mfma_f32_16x16x32_bf16(
                    a_cur[mi], b_cur[ni], acc1b[mi][ni], 0, 0, 0);
        if (k0i < 4)   // ELU of chunk0 row mi=k0i, hidden under this step's MFMAs
            elu_write_row(cbuf, acc1a[k0i], bi0[k0i],
                          wave * 64 + k0i * 16 + lq * 4, ln, sxr);
#pragma unroll
        for (int mi = 0; mi < 4; ++mi) a_cur[mi] = a_nxt[mi];
    }
    bar_lds();   // cbuf complete; mv reads done; W2 k0=0 loads stay in flight

    // chunk-1 biases for the interleaved ELU in P2-chunk0
    float4 bi1[4];
#pragma unroll
    for (int mi = 0; mi < 4; ++mi)
        bi1[mi] = *(const float4*)(b1 + 256 + wave * 64 + mi * 16 + lq * 4);

    floatx4 acc2[4][4];
#pragma unroll
    for (int mi = 0; mi < 4; ++mi)
#pragma unroll
        for (int ni = 0; ni < 4; ++ni) {
            floatx4 z = {0.0f, 0.0f, 0.0f, 0.0f};
            acc2[mi][ni] = z;
        }

    // ================= P2 super-region =======================================
    // ---- chunk 0 (W2 cols [0,256)), B = cbuf; ELU(chunk1) -> mv space ----
#pragma unroll
    for (int k0i = 0; k0i < 8; ++k0i) {
#pragma unroll
        for (int ni = 0; ni < 4; ++ni)
            b_cur[ni] = *(const short8*)((const char*)cbuf + (ni * 16 + ln) * 512
                                         + ((k0i * 64 + lq * 16) ^ sxr));
        const unsigned short* an = (k0i < 7) ? W2base + (k0i + 1) * 32
                                             : W2base + 256;        // chunk1 k0=0
#pragma unroll
        for (int mi = 0; mi < 4; ++mi)
            a_nxt[mi] = *(const short8*)(an + mi * 16 * NG);
#pragma unroll
        for (int ni = 0; ni < 4; ++ni)
#pragma unroll
            for (int mi = 0; mi < 4; ++mi)
                acc2[mi][ni] = __builtin_amdgcn_mfma_f32_16x16x32_bf16(
                    a_cur[mi], b_cur[ni], acc2[mi][ni], 0, 0, 0);
        if (k0i < 4)   // ELU of chunk1 row mi=k0i into mv's dead space (cbuf1)
            elu_write_row(mv, acc1b[k0i], bi1[k0i],
                          wave * 64 + k0i * 16 + lq * 4, ln, sxr);
#pragma unroll
        for (int mi = 0; mi < 4; ++mi) a_cur[mi] = a_nxt[mi];
    }
    bar_lds();   // cbuf1 (mv space) complete; W2 chunk1 k0=0 loads in flight
    // ---- chunk 1 (W2 cols [256,512)), B = mv space ----
#pragma unroll
    for (int k0i = 0; k0i < 8; ++k0i) {
#pragma unroll
        for (int ni = 0; ni < 4; ++ni)
            b_cur[ni] = *(const short8*)((const char*)mv + (ni * 16 + ln) * 512
                                         + ((k0i * 64 + lq * 16) ^ sxr));
        if (k0i < 7) {
            const unsigned short* an = W2base + 256 + (k0i + 1) * 32;
#pragma unroll
            for (int mi = 0; mi < 4; ++mi)
                a_nxt[mi] = *(const short8*)(an + mi * 16 * NG);
        }
#pragma unroll
        for (int ni = 0; ni < 4; ++ni)
#pragma unroll
            for (int mi = 0; mi < 4; ++mi)
                acc2[mi][ni] = __builtin_amdgcn_mfma_f32_16x16x32_bf16(
                    a_cur[mi], b_cur[ni], acc2[mi][ni], 0, 0, 0);
#pragma unroll
        for (int mi = 0; mi < 4; ++mi) a_cur[mi] = a_nxt[mi];
    }

    // ---- phase 3: fsi[b] = b3 + sum_n' ELU(h2[b][n'] + b2) * W3[n'] ----
    // part[] lives in cbuf space; last cbuf readers finished before the mid-P2
    // barrier, so writes here are safe; final barrier orders the reduction.
    float* part = (float*)cbuf;
    float w3v[4][4], b2v[4][4];
#pragma unroll
    for (int mi = 0; mi < 4; ++mi) {
        const int np = wave * 64 + mi * 16 + lq * 4;
        const float4 wv = *(const float4*)(W3 + np);
        const float4 bv = *(const float4*)(b2 + np);
        w3v[mi][0] = wv.x; w3v[mi][1] = wv.y; w3v[mi][2] = wv.z; w3v[mi][3] = wv.w;
        b2v[mi][0] = bv.x; b2v[mi][1] = bv.y; b2v[mi][2] = bv.z; b2v[mi][3] = bv.w;
    }
#pragma unroll
    for (int ni = 0; ni < 4; ++ni) {
        float s = 0.0f;
#pragma unroll
        for (int mi = 0; mi < 4; ++mi)
#pragma unroll
            for (int rg = 0; rg < 4; ++rg)
                s += elu1(acc2[mi][ni][rg] + b2v[mi][rg]) * w3v[mi][rg];
        s += __shfl_xor(s, 16);
        s += __shfl_xor(s, 32);
        if (lq == 0) part[wave * 64 + ni * 16 + ln] = s;
    }
    bar_lds();
    if (t < 64) {
        float s = b3[0];
#pragma unroll
        for (int w = 0; w < 4; ++w) s += part[w * 64 + t];
        fsi[(size_t)kidx * NB + b0 + t] = s;
    }
}

// ---------------- kernel 2: softmax over rules + consequent + weighted sum ----------------
// grid: 512 blocks x 512 threads; block = 16 batch rows, 64 classes.
// Waves 0-3 handle rules 0-7, waves 4-7 handle rules 8-15 (2x wave parallelism,
// 16 waves/CU); dual-rule unroll gives 2 independent MFMA chains per wave.
__global__ __launch_bounds__(512, 4) void cons_kernel(
    const float* __restrict__ x, const unsigned short* __restrict__ Wcb,
    const float* __restrict__ bc, const float* __restrict__ fsi,
    const int* __restrict__ ridx, float* __restrict__ outp,
    float* __restrict__ fire_out)
{
    __shared__ unsigned short xl[16 * 264];
    __shared__ float fire[16][NK];
    __shared__ float pred[4][16][16];   // half-1 partials: [class-grp][row][class]

    const int t  = threadIdx.x;
    const int b0 = blockIdx.x * 16;

    int rr[NK];
#pragma unroll
    for (int k = 0; k < NK; ++k) rr[k] = ridx[k];

    // x -> bf16 LDS (16 rows x 256 cols, 512 threads x 2 float4)
    {
        int idx = t;
#pragma unroll
        for (int i = 0; i < 2; ++i, idx += 512) {
            int row = idx >> 6, col = (idx & 63) * 4;
            const float4 xv = *(const float4*)(x + (size_t)(b0 + row) * NF + col);
            union { unsigned short s[4]; uint2 v; } pk;
            pk.s[0] = f2bf(xv.x); pk.s[1] = f2bf(xv.y);
            pk.s[2] = f2bf(xv.z); pk.s[3] = f2bf(xv.w);
            *(uint2*)(xl + row * 264 + col) = pk.v;
        }
    }
    // softmax over 16 rules, fully parallel: thread = (row = t>>4, k = t&15)
    if (t < 256) {
        const int row = t >> 4, k = t & 15;
        float v = fsi[(size_t)k * NB + b0 + row];
        float mx = v;
        mx = fmaxf(mx, __shfl_xor(mx, 1));
        mx = fmaxf(mx, __shfl_xor(mx, 2));
        mx = fmaxf(mx, __shfl_xor(mx, 4));
        mx = fmaxf(mx, __shfl_xor(mx, 8));
        float e = __expf(v - mx);
        float sum = e;
        sum += __shfl_xor(sum, 1);
        sum += __shfl_xor(sum, 2);
        sum += __shfl_xor(sum, 4);
        sum += __shfl_xor(sum, 8);
        float fv = e / sum;
        fire[row][k] = fv;
        fire_out[(size_t)b0 * NK + t] = fv;   // (b0+row)*16 + k == b0*16 + t
    }
    __syncthreads();

    const int wave = t >> 6, lane = t & 63;
    const int ln = lane & 15, lq = lane >> 4;
    const int cg = wave & 3, half = wave >> 2;
    const int nb = cg * 16;

    // A-fragments (x tile) cached in registers, reused across this half's 8 rules
    short8 afr[8];
#pragma unroll
    for (int k0i = 0; k0i < 8; ++k0i)
        afr[k0i] = *(const short8*)(xl + ln * 264 + k0i * 32 + lq * 8);

    floatx4 oacc = {0.0f, 0.0f, 0.0f, 0.0f};
#pragma unroll
    for (int kp = 0; kp < 4; ++kp) {
        const int k0r = half * 8 + kp * 2;
        const int r0 = rr[k0r], r1 = rr[k0r + 1];
        const unsigned short* Wr0 = Wcb + ((size_t)r0 * NC + nb + ln) * NF;
        const unsigned short* Wr1 = Wcb + ((size_t)r1 * NC + nb + ln) * NF;
        floatx4 a0 = {0.0f, 0.0f, 0.0f, 0.0f};
        floatx4 a1 = {0.0f, 0.0f, 0.0f, 0.0f};
#pragma unroll
        for (int k0i = 0; k0i < 8; ++k0i) {
            short8 bb0 = *(const short8*)(Wr0 + k0i * 32 + lq * 8);
            short8 bb1 = *(const short8*)(Wr1 + k0i * 32 + lq * 8);
            a0 = __builtin_amdgcn_mfma_f32_16x16x32_bf16(afr[k0i], bb0, a0, 0, 0, 0);
            a1 = __builtin_amdgcn_mfma_f32_16x16x32_bf16(afr[k0i], bb1, a1, 0, 0, 0);
        }
        const float bias0 = bc[(size_t)r0 * NC + nb + ln];
        const float bias1 = bc[(size_t)r1 * NC + nb + ln];
#pragma unroll
        for (int rg = 0; rg < 4; ++rg) {
            const int row = lq * 4 + rg;
            oacc[rg] += fmaxf(a0[rg] + bias0, 0.0f) * fire[row][k0r]
                      + fmaxf(a1[rg] + bias1, 0.0f) * fire[row][k0r + 1];
        }
    }
    if (half == 1) {
#pragma unroll
        for (int rg = 0; rg < 4; ++rg)
            pred[cg][lq * 4 + rg][ln] = oacc[rg];
    }
    __syncthreads();
    if (half == 0) {
#pragma unroll
        for (int rg = 0; rg < 4; ++rg)
            outp[(size_t)(b0 + lq * 4 + rg) * NC + nb + ln] =
                oacc[rg] + pred[cg][lq * 4 + rg][ln];
    }
}

extern "C" void kernel_launch(void* const* d_in, const int* in_sizes, int n_in,
                              void* d_out, int out_size, void* d_ws, size_t ws_size,
                              hipStream_t stream)
{
    (void)in_sizes; (void)n_in; (void)out_size;
    if (ws_size < 2097152) return;  // 1.5MB bf16 weights + 0.5MB fsi

    const float* x     = (const float*)d_in[0];
    const float* proto = (const float*)d_in[1];
    const float* var   = (const float*)d_in[2];
    const float* W1    = (const float*)d_in[3];
    const float* b1    = (const float*)d_in[4];
    const float* W2    = (const float*)d_in[5];
    const float* b2    = (const float*)d_in[6];
    const float* W3    = (const float*)d_in[7];
    const float* b3    = (const float*)d_in[8];
    const float* Wc    = (const float*)d_in[9];
    const float* bc    = (const float*)d_in[10];
    const int*   ridx  = (const int*)d_in[11];

    unsigned short* wb  = (unsigned short*)d_ws;
    unsigned short* W1b = wb;                 // 131072
    unsigned short* W2b = wb + 131072;        // 131072
    unsigned short* Wcb = wb + 262144;        // 524288
    float* fsi = (float*)((char*)d_ws + (size_t)786432 * 2);  // 16*8192 floats

    float* outp     = (float*)d_out;
    float* fire_out = outp + (size_t)NB * NC;

    conv_kernel<<<3072, 256, 0, stream>>>(W1, W2, Wc, wb);

    const int fs_lds = 2 * 64 * 256 * 2;  // 65536 B
    hipFuncSetAttribute((const void*)fs_kernel,
                        hipFuncAttributeMaxDynamicSharedMemorySize, fs_lds);
    fs_kernel<<<2048, 256, fs_lds, stream>>>(x, proto, var, W1b, b1, W2b, b2,
                                             W3, b3, ridx, fsi);
    cons_kernel<<<512, 512, 0, stream>>>(x, Wcb, bc, fsi, ridx, outp, fire_out);
}